// Round 13
// baseline (359.618 us; speedup 1.0000x reference)
//
#include <hip/hip_runtime.h>
#include <math.h>

// ---------------------------------------------------------------------------
// GCN: x[N,128] -> conv1(W1[128,32]) -> relu -> conv2(W2[32,16]) -> fc heads
// Outputs (concat): r[N], x1f[N]
//
// CSR-pull v11. vs verified v9 (350.8 us):
//   - Single edge buffer: partB node-sorts IN PLACE (LDS-staged permutation,
//     128-node buckets, CAP 6912 = mean+45sigma, global-scratch fallback for
//     oversized buckets). Frees big[] from the tmp overlay.
//   - fusedA launch: placeA blocks + gemm1 blocks (512 thr) run CONCURRENTLY;
//     gemm1 writes unscaled h1 and hides under placeA.
//   - partB epilogue scales g1 rows by dinv (16 KB/block, coalesced), so
//     gather32_fused / final_scalar are byte-identical to verified v9.
// Workspace: (66N + 2E + 2K + 2)*4 ~= 52.0 MB.
// ---------------------------------------------------------------------------

#define TPB 256
#define CNT_CHUNK 4096
#define PLC_CHUNK 3584     // 7 edges/thread at 512 threads
#define KMAXB 1024         // scan-padded bucket array size
#define BSH 7              // 128 nodes per bucket
#define BMSK 127
#define PB_CAP 6912        // partB LDS stage capacity (edges)
#define NPW 8              // nodes per wave in the gather kernels

// ---------------- phase 1: per-bucket edge counts --------------------------
__global__ __launch_bounds__(512) void countA_kernel(const int* __restrict__ dst,
                                                     int* __restrict__ gtot,
                                                     int E, int K) {
    __shared__ int lhist[KMAXB];
    const int tid = threadIdx.x;
    const int e0  = blockIdx.x * CNT_CHUNK;
    lhist[tid] = 0; lhist[tid + 512] = 0;
    __syncthreads();
#pragma unroll
    for (int i = 0; i < 8; ++i) {
        int e = e0 + tid + i * 512;
        if (e < E) atomicAdd(&lhist[dst[e] >> BSH], 1);
    }
    __syncthreads();
    for (int b = tid; b < K; b += 512)
        if (lhist[b] > 0) atomicAdd(&gtot[b], lhist[b]);
}

// ------- phase 2: scan totals -> gstart[K+1]; gcursor = gstart; spill=0 ----
__global__ __launch_bounds__(64) void kscan_kernel(const int* __restrict__ gtot,
                                                   int* __restrict__ gstart,
                                                   int* __restrict__ gcursor,
                                                   int* __restrict__ spill,
                                                   int K, int E) {
    int tid = threadIdx.x;                  // one wave, 13 bins/lane (K<=832)
    int b0 = tid * 13, v[13], s = 0;
#pragma unroll
    for (int t = 0; t < 13; ++t) {
        v[t] = s;
        int idx = b0 + t;
        s += (idx < K) ? gtot[idx] : 0;
    }
    int incl = s;
#pragma unroll
    for (int d = 1; d < 64; d <<= 1) {
        int t2 = __shfl_up(incl, d);
        if (tid >= d) incl += t2;
    }
    int excl = incl - s;
#pragma unroll
    for (int t = 0; t < 13; ++t) {
        int idx = b0 + t;
        if (idx < K) { gstart[idx] = excl + v[t]; gcursor[idx] = excl + v[t]; }
    }
    if (tid == 0) { gstart[K] = E; spill[0] = 0; }
}

// -------- phase 3 (fused): placeA blocks [0,PB) || gemm1 blocks [PB,..) ----
// placeA: LDS histogram + scan + absolute-range reservation + LDS-staged
//         reorder; streams bucket-sorted packed edges into ebuf.
// gemm1:  h1[N,32] = x[N,128] @ W1 (UNSCALED; dinv applied by partB).
__global__ __launch_bounds__(512) void fusedA_kernel(const int* __restrict__ src,
                                                     const int* __restrict__ dst,
                                                     const float* __restrict__ ew,
                                                     uint2* __restrict__ ebuf,
                                                     int* __restrict__ gcursor,
                                                     const float* __restrict__ x,
                                                     const float* __restrict__ W,
                                                     float* __restrict__ h,
                                                     int E, int K, int N, int PB) {
    __shared__ __align__(16) char smem[59392];
    const int tid = threadIdx.x;

    if ((int)blockIdx.x < PB) {
        // ---------------- placeA role ----------------
        int*   lhist  = (int*)smem;                  // 1024
        int*   lbase  = (int*)(smem + 4096);         // 1024
        int*   lcur   = (int*)(smem + 8192);         // 1024
        int*   gbaseS = (int*)(smem + 12288);        // 1024
        uint2* stage  = (uint2*)(smem + 16384);      // 3584
        int*   saddr  = (int*)(smem + 45056);        // 3584
        const int e0 = blockIdx.x * PLC_CHUNK;

        lhist[tid] = 0; lhist[tid + 512] = 0;
        lcur[tid]  = 0; lcur[tid + 512]  = 0;
        __syncthreads();

        int   b[7];
        uint2 p[7];
#pragma unroll
        for (int i = 0; i < 7; ++i) {
            int e = e0 + tid + i * 512;
            b[i] = -1;
            if (e < E) {
                int d   = dst[e];
                b[i]   = d >> BSH;
                p[i].x = __float_as_uint(ew[e]);
                p[i].y = ((unsigned)src[e] << BSH) | (unsigned)(d & BMSK);
                atomicAdd(&lhist[b[i]], 1);
            }
        }
        __syncthreads();

        // exclusive scan of 1024 (zero-padded) bins: one wave, 16 bins/lane
        __shared__ int ltot;
        if (tid < 64) {
            int b0 = tid * 16, v[16], s = 0;
#pragma unroll
            for (int t = 0; t < 16; ++t) { v[t] = s; s += lhist[b0 + t]; }
            int incl = s;
#pragma unroll
            for (int d = 1; d < 64; d <<= 1) {
                int t2 = __shfl_up(incl, d);
                if (tid >= d) incl += t2;
            }
            int excl = incl - s;
#pragma unroll
            for (int t = 0; t < 16; ++t) lbase[b0 + t] = excl + v[t];
            if (tid == 63) ltot = incl;
        }
        __syncthreads();

        for (int bk = tid; bk < K; bk += 512)
            if (lhist[bk] > 0) gbaseS[bk] = atomicAdd(&gcursor[bk], lhist[bk]);
        __syncthreads();

#pragma unroll
        for (int i = 0; i < 7; ++i) {
            if (b[i] >= 0) {
                int r    = atomicAdd(&lcur[b[i]], 1);
                int sidx = lbase[b[i]] + r;
                stage[sidx] = p[i];
                saddr[sidx] = gbaseS[b[i]] + r;
            }
        }
        __syncthreads();

        int tot = ltot;
        for (int s = tid; s < tot; s += 512) ebuf[saddr[s]] = stage[s];
    } else {
        // ---------------- gemm1 role (64 nodes / block) ----------------
        float* Ws = (float*)smem;                    // 128*32
        float* xs = (float*)smem + 4096;             // 64*129
        const int nb = ((int)blockIdx.x - PB) * 64;

        const float4* W4  = (const float4*)W;
        float4*       Ws4 = (float4*)Ws;
#pragma unroll
        for (int i = 0; i < 2; ++i) Ws4[tid + i * 512] = W4[tid + i * 512];

#pragma unroll
        for (int i = 0; i < 4; ++i) {
            int idx  = tid + i * 512;
            int node = idx >> 5;
            int col4 = idx & 31;
            if (nb + node < N) {
                float4 v = ((const float4*)(x + (size_t)nb * 128))[idx];
                float* p = &xs[node * 129 + col4 * 4];
                p[0] = v.x; p[1] = v.y; p[2] = v.z; p[3] = v.w;
            }
        }
        __syncthreads();

        const int nl = tid >> 3;           // 0..63
        const int og = (tid & 7) * 4;
        float a0 = 0.f, a1 = 0.f, a2 = 0.f, a3 = 0.f;
#pragma unroll 8
        for (int k = 0; k < 128; ++k) {
            float xv = xs[nl * 129 + k];
            const float* wp = &Ws[k * 32 + og];
            a0 = fmaf(xv, wp[0], a0);
            a1 = fmaf(xv, wp[1], a1);
            a2 = fmaf(xv, wp[2], a2);
            a3 = fmaf(xv, wp[3], a3);
        }
        int node = nb + nl;
        if (node < N) {
            float* out = &h[(size_t)node * 32 + og];
            out[0] = a0; out[1] = a1; out[2] = a2; out[3] = a3;  // unscaled
        }
    }
}

// -------- phase 4: in-place per-bucket node sort + dinv + g1 scaling -------
__global__ __launch_bounds__(512) void partB_kernel(uint2* __restrict__ ebuf,
                                                    const int* __restrict__ gstart,
                                                    int* __restrict__ off,
                                                    float* __restrict__ dinv,
                                                    float* __restrict__ g1,
                                                    uint2* __restrict__ scratch,
                                                    int* __restrict__ spill,
                                                    int N) {
    __shared__ uint2 seg[PB_CAP];                    // 55296 B
    __shared__ int   lhist[128], loff[128], lcur[128];
    __shared__ float ldeg[128];
    __shared__ int   sbase;
    const int tid  = threadIdx.x;
    const int k    = blockIdx.x;
    const int seg0 = gstart[k], seg1 = gstart[k + 1];
    const int cnt  = seg1 - seg0;

    if (tid < 128) { lhist[tid] = 0; lcur[tid] = 0; ldeg[tid] = 0.f; }
    __syncthreads();

    if (cnt <= PB_CAP) {
        // normal path: stage whole segment in LDS, permute in place
        for (int j = seg0 + tid; j < seg1; j += 512) seg[j - seg0] = ebuf[j];
        __syncthreads();
        for (int t = tid; t < cnt; t += 512)
            atomicAdd(&lhist[seg[t].y & (unsigned)BMSK], 1);
        __syncthreads();

        if (tid < 64) {                    // scan 128 bins, 2/lane
            int b0 = tid * 2, v0, v1, s;
            v0 = 0; v1 = lhist[b0]; s = v1 + lhist[b0 + 1];
            int incl = s;
#pragma unroll
            for (int d = 1; d < 64; d <<= 1) {
                int t2 = __shfl_up(incl, d);
                if (tid >= d) incl += t2;
            }
            int excl = incl - s;
            loff[b0] = excl + v0; loff[b0 + 1] = excl + v1;
        }
        __syncthreads();

        if (tid < 128) {
            int d = (k << BSH) + tid;
            if (d < N) off[d] = seg0 + loff[tid];
        }

        for (int t = tid; t < cnt; t += 512) {
            uint2 q  = seg[t];
            int dlow = q.y & (unsigned)BMSK;
            int r    = atomicAdd(&lcur[dlow], 1);
            uint2 pr; pr.x = q.y >> BSH; pr.y = q.x;   // {src, w}
            ebuf[seg0 + loff[dlow] + r] = pr;
            atomicAdd(&ldeg[dlow], __uint_as_float(q.x));
        }
        __syncthreads();
    } else {
        // fallback: oversized bucket via global scratch (correct, rare)
        for (int j = seg0 + tid; j < seg1; j += 512)
            atomicAdd(&lhist[ebuf[j].y & (unsigned)BMSK], 1);
        __syncthreads();
        if (tid < 64) {
            int b0 = tid * 2, v0, v1, s;
            v0 = 0; v1 = lhist[b0]; s = v1 + lhist[b0 + 1];
            int incl = s;
#pragma unroll
            for (int d = 1; d < 64; d <<= 1) {
                int t2 = __shfl_up(incl, d);
                if (tid >= d) incl += t2;
            }
            int excl = incl - s;
            loff[b0] = excl + v0; loff[b0 + 1] = excl + v1;
        }
        __syncthreads();
        if (tid < 128) {
            int d = (k << BSH) + tid;
            if (d < N) off[d] = seg0 + loff[tid];
        }
        if (tid == 0) sbase = atomicAdd(spill, cnt);
        __syncthreads();
        for (int j = seg0 + tid; j < seg1; j += 512) {
            uint2 q  = ebuf[j];
            int dlow = q.y & (unsigned)BMSK;
            int r    = atomicAdd(&lcur[dlow], 1);
            scratch[sbase + loff[dlow] + r] = q;
            atomicAdd(&ldeg[dlow], __uint_as_float(q.x));
        }
        __syncthreads();
        for (int t = tid; t < cnt; t += 512) {
            uint2 q = scratch[sbase + t];
            uint2 pr; pr.x = q.y >> BSH; pr.y = q.x;
            ebuf[seg0 + t] = pr;
        }
        __syncthreads();
    }

    // dinv + scale this bucket's g1 rows (written unscaled by fusedA/gemm1)
    if (tid < 128) ldeg[tid] = 1.0f / sqrtf(ldeg[tid] + 1.0f);
    __syncthreads();
    if (tid < 128) {
        int d = (k << BSH) + tid;
        if (d < N) dinv[d] = ldeg[tid];
    }
    const int base = (k << BSH);
    for (int t = tid; t < 128 * 32; t += 512) {
        int nl = t >> 5;
        int d  = base + nl;
        if (d < N) g1[(size_t)d * 32 + (t & 31)] *= ldeg[nl];
    }
}

// Pull-mode conv1 fused with relu, gemm2, the fc2 dot, AND the fc1 dot.
// (byte-identical to verified v9)
__global__ __launch_bounds__(TPB) void gather32_fused_kernel(
    const int* __restrict__ off, const int2* __restrict__ epair,
    const float* __restrict__ g1, const float* __restrict__ dinv,
    const float* __restrict__ b1, const float* __restrict__ W2,
    const float* __restrict__ fc1_w, const float* __restrict__ fc2_w,
    float* __restrict__ z, float* __restrict__ rdot, int N, int E) {
    __shared__ float wls[560];  // [0..511]=W2, [512..543]=fc2_w, [544..559]=fc1_w
    const int tid = threadIdx.x;
    wls[tid]       = W2[tid];
    wls[tid + 256] = W2[tid + 256];
    if (tid < 32)      wls[512 + tid] = fc2_w[tid];
    else if (tid < 48) wls[512 + tid] = fc1_w[tid - 32];
    __syncthreads();

    const int lane = tid & 63;
    const int f    = lane & 31;
    const int half = lane >> 5;
    const float bv = b1[f];
    const int wbase = (lane < 16) ? lane : 512;
    const int wstrd = (lane < 16) ? 16 : 1;
    const float f1v = wls[544 + (lane & 15)];

    const int i0 = (blockIdx.x * (TPB / 64) + (tid >> 6)) * NPW;

    for (int t = 0; t < NPW; ++t) {
        int i = i0 + t;
        if (i >= N) return;
        const int s0 = off[i];
        const int s1 = (i + 1 < N) ? off[i + 1] : E;

        float acc = 0.f;
        int j = s0 + half;
        for (; j + 6 < s1; j += 8) {           // 4-edge unroll per half
            int2 pa = epair[j];
            int2 pb = epair[j + 2];
            int2 pc = epair[j + 4];
            int2 pd = epair[j + 6];
            acc = fmaf(__int_as_float(pa.y), g1[(size_t)pa.x * 32 + f], acc);
            acc = fmaf(__int_as_float(pb.y), g1[(size_t)pb.x * 32 + f], acc);
            acc = fmaf(__int_as_float(pc.y), g1[(size_t)pc.x * 32 + f], acc);
            acc = fmaf(__int_as_float(pd.y), g1[(size_t)pd.x * 32 + f], acc);
        }
        for (; j < s1; j += 2) {
            int2 p = epair[j];
            acc = fmaf(__int_as_float(p.y), g1[(size_t)p.x * 32 + f], acc);
        }
        acc += __shfl_xor(acc, 32);

        float dv = dinv[i];
        float v  = fmaxf(dv * (acc + g1[(size_t)i * 32 + f]) + bv, 0.f);

        float hs = 0.f;
#pragma unroll
        for (int k = 0; k < 32; ++k)
            hs = fmaf(__shfl(v, k), wls[wbase + k * wstrd], hs);

        float zp = hs * dv * f1v;
        zp += __shfl_xor(zp, 1);
        zp += __shfl_xor(zp, 2);
        zp += __shfl_xor(zp, 4);
        zp += __shfl_xor(zp, 8);

        if (lane == 0)       z[i]    = zp;
        else if (lane == 16) rdot[i] = hs;
    }
}

// Scalar conv2 aggregation + full epilogue. (byte-identical to verified v9)
__global__ __launch_bounds__(TPB) void final_scalar_kernel(
    const int* __restrict__ off, const int2* __restrict__ epair,
    const float* __restrict__ z, const float* __restrict__ rdot,
    const float* __restrict__ dinv, const float* __restrict__ b2,
    const float* __restrict__ fc1_w, const float* __restrict__ fc1_b,
    const float* __restrict__ fc2_w, const float* __restrict__ fc2_b,
    float* __restrict__ out, int N, int E) {
    const int tid  = threadIdx.x;
    const int lane = tid & 63;

    float C = fc1_b[0];
#pragma unroll
    for (int f = 0; f < 16; ++f) C = fmaf(b2[f], fc1_w[f], C);
    const float f2w = fc2_w[32];
    const float f2b = fc2_b[0];

    const int i0 = (blockIdx.x * (TPB / 64) + (tid >> 6)) * NPW;

    for (int t = 0; t < NPW; ++t) {
        int i = i0 + t;
        if (i >= N) return;
        const int s0 = off[i];
        const int s1 = (i + 1 < N) ? off[i + 1] : E;

        float acc = 0.f;
        for (int j = s0 + lane; j < s1; j += 64) {
            int2 p = epair[j];
            acc = fmaf(__int_as_float(p.y), z[p.x], acc);
        }
        acc += __shfl_xor(acc, 1);
        acc += __shfl_xor(acc, 2);
        acc += __shfl_xor(acc, 4);
        acc += __shfl_xor(acc, 8);
        acc += __shfl_xor(acc, 16);
        acc += __shfl_xor(acc, 32);

        float x1f = dinv[i] * (acc + z[i]) + C;
        float c   = 1.0f / (1.0f + expf(-x1f));
        float r   = fmaf(c, f2w, f2b) + rdot[i];

        if (lane == 0) {
            out[i]     = r;
            out[N + i] = x1f;
        }
    }
}

extern "C" void kernel_launch(void* const* d_in, const int* in_sizes, int n_in,
                              void* d_out, int out_size, void* d_ws, size_t ws_size,
                              hipStream_t stream) {
    const float* x     = (const float*)d_in[0];
    const int*   ei    = (const int*)d_in[1];
    const float* ew    = (const float*)d_in[2];
    const float* W1    = (const float*)d_in[3];
    const float* b1    = (const float*)d_in[4];
    const float* W2    = (const float*)d_in[5];
    const float* b2    = (const float*)d_in[6];
    const float* fc1_w = (const float*)d_in[7];
    const float* fc1_b = (const float*)d_in[8];
    const float* fc2_w = (const float*)d_in[9];
    const float* fc2_b = (const float*)d_in[10];

    const int N = in_sizes[0] / 128;
    const int E = in_sizes[2];
    const int* src = ei;
    const int* dst = ei + E;
    const int K = (N + BMSK) >> BSH;       // 128-node buckets

    // workspace (floats):
    //   dinv[N] | big[64N]: g1[0..32N) | scratch[32N..48N) | rdot@48N | z@49N
    //   | off[N] | ebuf[E] uint2/int2 | gcursor[K] | gstart[K+1] | spill[1]
    float* ws    = (float*)d_ws;
    float* dinv  = ws;
    float* big   = dinv + N;
    float* g1    = big;                            // 32N
    uint2* scratch = (uint2*)(big + (size_t)32 * N); // 8N edges capacity
    float* rdot  = big + (size_t)48 * N;           // N
    float* z     = big + (size_t)49 * N;           // N
    int*   off   = (int*)(big + (size_t)64 * N);
    uint2* ebuf  = (uint2*)(off + N);              // E
    int*   gcursor = (int*)(ebuf + E);
    int*   gstart  = gcursor + K;
    int*   spill   = gstart + K + 1;

    size_t need = ((size_t)66 * N + (size_t)2 * E + 2 * K + 2) * 4;
    if (ws_size < need || K > 832 || (size_t)E > (size_t)32 * N) return;

    hipMemsetAsync(gcursor, 0, (size_t)K * sizeof(int), stream);

    const int CB = (E + CNT_CHUNK - 1) / CNT_CHUNK;
    const int PB = (E + PLC_CHUNK - 1) / PLC_CHUNK;
    const int GB = (N + 63) / 64;

    countA_kernel<<<CB, 512, 0, stream>>>(dst, gcursor, E, K);
    kscan_kernel<<<1, 64, 0, stream>>>(gcursor, gstart, gcursor, spill, K, E);
    fusedA_kernel<<<PB + GB, 512, 0, stream>>>(src, dst, ew, ebuf, gcursor,
                                               x, W1, g1, E, K, N, PB);
    partB_kernel<<<K, 512, 0, stream>>>(ebuf, gstart, off, dinv, g1,
                                        scratch, spill, N);

    const int gblocks = (N + 4 * NPW - 1) / (4 * NPW);
    gather32_fused_kernel<<<gblocks, TPB, 0, stream>>>(
        off, (const int2*)ebuf, g1, dinv, b1, W2, fc1_w, fc2_w, z, rdot, N, E);
    final_scalar_kernel<<<gblocks, TPB, 0, stream>>>(
        off, (const int2*)ebuf, z, rdot, dinv, b2, fc1_w, fc1_b, fc2_w, fc2_b,
        (float*)d_out, N, E);
}